// Round 1
// baseline (903.198 us; speedup 1.0000x reference)
//
#include <hip/hip_runtime.h>

#define BATCH 32
#define NN 512
#define NODE_F 64
#define EDGE_F 16
#define MSG 80        // NODE_F + EDGE_F
#define OUTF 64
#define RD 128        // readout dim (OUT[3])
#define TGT 16
#define KMAX 8        // compact-adjacency cap; fallback to dense scan beyond
#define ROWS (BATCH*NN)  // 16384

// ---------------------------------------------------------------------------
// K1: per (b,v) row of g: degree, compact adjacency (<=KMAX), me = sum g*e
// one wave (64 lanes) per row; 4 waves per 256-thread block
// ---------------------------------------------------------------------------
__global__ __launch_bounds__(256) void preprocess_kernel(
    const float* __restrict__ g, const float* __restrict__ e,
    int* __restrict__ adj_idx, float* __restrict__ adj_val,
    int* __restrict__ nnzArr, int* __restrict__ bucketArr,
    float* __restrict__ me)
{
  __shared__ int   s_idx[4][KMAX];
  __shared__ float s_val[4][KMAX];
  int lane = threadIdx.x & 63;
  int wid  = threadIdx.x >> 6;
  int row  = blockIdx.x * 4 + wid;
  const float* grow = g + (size_t)row * NN;
  float deg = 0.f;
  int cnt = 0;
  for (int it = 0; it < NN/64; ++it) {        // uniform trip count (sync-safe)
    int w = it*64 + lane;
    float gv = grow[w];
    deg += gv;
    unsigned long long m = __ballot(gv != 0.0f);
    int before = __popcll(m & ((1ull << lane) - 1ull));
    if (gv != 0.0f) {
      int pos = cnt + before;
      if (pos < KMAX) { s_idx[wid][pos] = w; s_val[wid][pos] = gv; }
    }
    cnt += __popcll(m);
  }
  for (int off = 32; off; off >>= 1) deg += __shfl_xor(deg, off);
  __syncthreads();                            // publish s_idx/s_val
  const float* erow = e + (size_t)row * NN * EDGE_F;
  float mef = 0.f;
  if (cnt <= KMAX) {
    for (int k = 0; k < cnt; ++k) {           // wave-uniform loop
      int   wk = s_idx[wid][k];
      float vk = s_val[wid][k];
      if (lane < EDGE_F) mef += vk * erow[wk*EDGE_F + lane];
    }
  } else {                                    // general fallback: dense row
    for (int w = 0; w < NN; ++w) {
      float gv = grow[w];
      if (gv != 0.f && lane < EDGE_F) mef += gv * erow[w*EDGE_F + lane];
    }
  }
  if (lane < EDGE_F) me[(size_t)row*EDGE_F + lane] = mef;
  if (lane < KMAX && lane < cnt) {
    adj_idx[row*KMAX + lane] = s_idx[wid][lane];
    adj_val[row*KMAX + lane] = s_val[wid][lane];
  }
  if (lane == 0) {
    int bk = -1;                              // deg not in {1,2,3,4} -> h'=0
    if      (deg == 1.0f) bk = 0;
    else if (deg == 2.0f) bk = 1;
    else if (deg == 3.0f) bk = 2;
    else if (deg == 4.0f) bk = 3;
    bucketArr[row] = bk;
    nnzArr[row] = cnt;
  }
}

// ---------------------------------------------------------------------------
// K2: bucket-sort node ids so step blocks share one H matrix
// ---------------------------------------------------------------------------
__global__ void scatter_kernel(const int* __restrict__ bucketArr,
                               int* __restrict__ counts, int* __restrict__ perm)
{
  int i = blockIdx.x * blockDim.x + threadIdx.x;
  if (i < ROWS) {
    int bk = bucketArr[i];
    if (bk >= 0) {
      int p = atomicAdd(&counts[bk], 1);
      perm[bk*ROWS + p] = i;
    }
  }
}

// ---------------------------------------------------------------------------
// K3 (x3): h_out[v] = concat(sum_nbr h_prev, me) @ H[bucket]
// block = 256 thr, 16 same-bucket nodes; wave w loads nodes w,w+4,w+8,w+12
// then thread (q=tid/64, o=tid&63) computes 4 outputs sharing each H read
// ---------------------------------------------------------------------------
__global__ __launch_bounds__(256) void step_kernel(
    const float* __restrict__ h_prev, float* __restrict__ h_out,
    const float* __restrict__ Ht,
    const int* __restrict__ perm, const int* __restrict__ counts,
    const int* __restrict__ nnzArr, const int* __restrict__ adj_idx,
    const float* __restrict__ adj_val, const float* __restrict__ me,
    const float* __restrict__ g)
{
  int d = blockIdx.x >> 10;
  int chunk = blockIdx.x & 1023;
  int cnt = counts[d];
  int base = chunk * 16;
  if (base >= cnt) return;                    // uniform early-exit
  __shared__ float sm[16][MSG];
  __shared__ int   srow[16];
  int lane = threadIdx.x & 63;
  int wid  = threadIdx.x >> 6;
  for (int j = 0; j < 4; ++j) {
    int nl = wid + 4*j;
    int gi = base + nl;
    if (gi < cnt) {
      int row = perm[d*ROWS + gi];
      if (lane == 0) srow[nl] = row;
      int bb  = row >> 9;
      int nnz = nnzArr[row];
      float mh = 0.f;
      if (nnz <= KMAX) {
        for (int k = 0; k < nnz; ++k) {
          int   w  = adj_idx[row*KMAX + k];
          float vv = adj_val[row*KMAX + k];
          mh += vv * h_prev[((size_t)(bb*NN + w))*NODE_F + lane];
        }
      } else {
        const float* grow = g + (size_t)row * NN;
        for (int w = 0; w < NN; ++w) {
          float gv = grow[w];
          if (gv != 0.f) mh += gv * h_prev[((size_t)(bb*NN + w))*NODE_F + lane];
        }
      }
      sm[nl][lane] = mh;
      if (lane < EDGE_F) sm[nl][NODE_F + lane] = me[(size_t)row*EDGE_F + lane];
    } else {
      if (lane == 0) srow[nl] = -1;
      sm[nl][lane] = 0.f;
      if (lane < EDGE_F) sm[nl][NODE_F + lane] = 0.f;
    }
  }
  __syncthreads();
  const float* Hd = Ht + d * MSG * OUTF;
  int o = lane, q = wid;
  float a0=0.f, a1=0.f, a2=0.f, a3=0.f;
  for (int i = 0; i < MSG; ++i) {
    float hv = Hd[i*OUTF + o];                // coalesced, shared by 4 nodes
    a0 += sm[q   ][i]*hv;                     // LDS broadcast reads
    a1 += sm[q+ 4][i]*hv;
    a2 += sm[q+ 8][i]*hv;
    a3 += sm[q+12][i]*hv;
  }
  float av[4] = {a0,a1,a2,a3};
  for (int j = 0; j < 4; ++j) {
    int r = srow[q + 4*j];
    if (r >= 0) h_out[(size_t)r*OUTF + o] = av[j];
  }
}

// ---------------------------------------------------------------------------
// K4: readout — lin = h_l @ W_l, masked softmax, sum over nodes into acc[b]
// block = 128 thr (o = tid), 32 nodes of one batch b, one layer l
// W_l (32KB) + h tile (8KB) staged in LDS
// ---------------------------------------------------------------------------
__global__ __launch_bounds__(128) void readout_kernel(
    const float* __restrict__ h0, const float* __restrict__ h1,
    const float* __restrict__ h2, const float* __restrict__ h3,
    const float* __restrict__ W0, const float* __restrict__ W1,
    const float* __restrict__ W2, const float* __restrict__ W3,
    float* __restrict__ accv)
{
  int l = blockIdx.x >> 9;
  int chunk = blockIdx.x & 511;
  const float* hs = (l==0)?h0:(l==1)?h1:(l==2)?h2:h3;
  const float* Wl = (l==0)?W0:(l==1)?W1:(l==2)?W2:W3;
  __shared__ float sW[NODE_F*RD];
  __shared__ float sh[32*NODE_F];
  __shared__ float sred[2], sred2[2];
  __shared__ int   sflag[2];
  int tid = threadIdx.x;
  const float4* W4 = (const float4*)Wl;
  float4* sW4 = (float4*)sW;
  for (int i = tid; i < NODE_F*RD/4; i += 128) sW4[i] = W4[i];
  const float4* h4 = (const float4*)(hs + (size_t)chunk*32*NODE_F);
  float4* sh4 = (float4*)sh;
  for (int i = tid; i < 32*NODE_F/4; i += 128) sh4[i] = h4[i];
  __syncthreads();
  int o = tid, wid = tid >> 6, lane = tid & 63;
  int b = chunk >> 4;                         // 16 chunks per batch
  float accl = 0.f;
  for (int n = 0; n < 32; ++n) {
    float lin = 0.f;
    for (int i = 0; i < NODE_F; ++i) lin += sh[n*NODE_F+i] * sW[i*RD+o];
    float mx = lin;
    for (int off = 32; off; off >>= 1) mx = fmaxf(mx, __shfl_xor(mx, off));
    int anyw = (__ballot(lin != 0.f) != 0ull) ? 1 : 0;
    if (lane == 0) { sred[wid] = mx; sflag[wid] = anyw; }
    __syncthreads();
    mx = fmaxf(sred[0], sred[1]);
    int any = sflag[0] | sflag[1];
    float p = expf(lin - mx);
    float s = p;
    for (int off = 32; off; off >>= 1) s += __shfl_xor(s, off);
    if (lane == 0) sred2[wid] = s;
    __syncthreads();
    s = sred2[0] + sred2[1];
    if (any) accl += p / s;
    __syncthreads();                          // protect sred reuse
  }
  atomicAdd(&accv[b*RD + o], accl);           // 32 conflicting adds/address
}

// ---------------------------------------------------------------------------
// K5: out[b] = softmax(acc[b] @ W_final + b_final), 16-lane group softmax
// ---------------------------------------------------------------------------
__global__ __launch_bounds__(512) void final_kernel(
    const float* __restrict__ accv, const float* __restrict__ Wf,
    const float* __restrict__ bf, float* __restrict__ out)
{
  int tid = threadIdx.x;
  int b = tid >> 4, t = tid & 15;
  float v = bf[t];
  for (int i = 0; i < RD; ++i) v += accv[b*RD + i] * Wf[i*TGT + t];
  float mx = v;
  for (int off = 8; off; off >>= 1) mx = fmaxf(mx, __shfl_xor(mx, off, 16));
  float p = expf(v - mx);
  float s = p;
  for (int off = 8; off; off >>= 1) s += __shfl_xor(s, off, 16);
  out[tid] = p / s;
}

extern "C" void kernel_launch(void* const* d_in, const int* in_sizes, int n_in,
                              void* d_out, int out_size, void* d_ws, size_t ws_size,
                              hipStream_t stream)
{
  const float* g    = (const float*)d_in[0];
  const float* h_in = (const float*)d_in[1];
  const float* e    = (const float*)d_in[2];
  const float* H0   = (const float*)d_in[3];
  const float* H1   = (const float*)d_in[4];
  const float* H2   = (const float*)d_in[5];
  const float* W0   = (const float*)d_in[6];
  const float* W1   = (const float*)d_in[7];
  const float* W2   = (const float*)d_in[8];
  const float* W3   = (const float*)d_in[9];
  const float* Wf   = (const float*)d_in[10];
  const float* bf   = (const float*)d_in[11];
  float* out = (float*)d_out;

  char* base = (char*)d_ws;
  size_t off = 0;
  auto alloc = [&](size_t bytes) -> void* {
    void* p = base + off;
    off = (off + bytes + 255) & ~(size_t)255;
    return p;
  };
  int*   adj_idx   = (int*)  alloc((size_t)ROWS*KMAX*sizeof(int));
  float* adj_val   = (float*)alloc((size_t)ROWS*KMAX*sizeof(float));
  int*   nnzArr    = (int*)  alloc((size_t)ROWS*sizeof(int));
  int*   bucketArr = (int*)  alloc((size_t)ROWS*sizeof(int));
  float* me        = (float*)alloc((size_t)ROWS*EDGE_F*sizeof(float));
  int*   perm      = (int*)  alloc((size_t)4*ROWS*sizeof(int));
  int*   counts    = (int*)  alloc(4*sizeof(int) + (size_t)BATCH*RD*sizeof(float));
  float* accv      = (float*)(counts + 4);
  float* h1        = (float*)alloc((size_t)ROWS*NODE_F*sizeof(float)*3);
  float* h2 = h1 + (size_t)ROWS*NODE_F;
  float* h3 = h2 + (size_t)ROWS*NODE_F;

  // zero counts+acc (16400 B) and h1..h3 (bucket<0 nodes must read as 0)
  hipMemsetAsync(counts, 0, 4*sizeof(int) + (size_t)BATCH*RD*sizeof(float), stream);
  hipMemsetAsync(h1, 0, (size_t)ROWS*NODE_F*sizeof(float)*3, stream);

  preprocess_kernel<<<ROWS/4, 256, 0, stream>>>(g, e, adj_idx, adj_val, nnzArr, bucketArr, me);
  scatter_kernel<<<(ROWS+255)/256, 256, 0, stream>>>(bucketArr, counts, perm);
  step_kernel<<<4*1024, 256, 0, stream>>>(h_in, h1, H0, perm, counts, nnzArr, adj_idx, adj_val, me, g);
  step_kernel<<<4*1024, 256, 0, stream>>>(h1,   h2, H1, perm, counts, nnzArr, adj_idx, adj_val, me, g);
  step_kernel<<<4*1024, 256, 0, stream>>>(h2,   h3, H2, perm, counts, nnzArr, adj_idx, adj_val, me, g);
  readout_kernel<<<4*512, 128, 0, stream>>>(h_in, h1, h2, h3, W0, W1, W2, W3, accv);
  final_kernel<<<1, 512, 0, stream>>>(accv, Wf, bf, out);
}

// Round 2
// 870.255 us; speedup vs baseline: 1.0379x; 1.0379x over previous
//
#include <hip/hip_runtime.h>

#define BATCH 32
#define NN 512
#define NODE_F 64
#define EDGE_F 16
#define MSG 80        // NODE_F + EDGE_F
#define OUTF 64
#define RD 128        // readout dim (OUT[3])
#define TGT 16
#define KMAX 8        // compact-adjacency cap; fallback to dense scan beyond
#define ROWS (BATCH*NN)  // 16384

// ---------------------------------------------------------------------------
// K1: per (b,v) row of g: degree, compact adjacency (<=KMAX), me = sum g*e
// one wave (64 lanes) per row; 4 waves per 256-thread block
// ---------------------------------------------------------------------------
__global__ __launch_bounds__(256) void preprocess_kernel(
    const float* __restrict__ g, const float* __restrict__ e,
    int* __restrict__ adj_idx, float* __restrict__ adj_val,
    int* __restrict__ nnzArr, int* __restrict__ bucketArr,
    float* __restrict__ me)
{
  __shared__ int   s_idx[4][KMAX];
  __shared__ float s_val[4][KMAX];
  int lane = threadIdx.x & 63;
  int wid  = threadIdx.x >> 6;
  int row  = blockIdx.x * 4 + wid;
  const float* grow = g + (size_t)row * NN;
  float deg = 0.f;
  int cnt = 0;
  for (int it = 0; it < NN/64; ++it) {        // uniform trip count
    int w = it*64 + lane;
    float gv = grow[w];
    deg += gv;
    unsigned long long m = __ballot(gv != 0.0f);
    int before = __popcll(m & ((1ull << lane) - 1ull));
    if (gv != 0.0f) {
      int pos = cnt + before;
      if (pos < KMAX) { s_idx[wid][pos] = w; s_val[wid][pos] = gv; }
    }
    cnt += __popcll(m);
  }
  for (int off = 32; off; off >>= 1) deg += __shfl_xor(deg, off);
  __syncthreads();
  const float* erow = e + (size_t)row * NN * EDGE_F;
  float mef = 0.f;
  if (cnt <= KMAX) {
    for (int k = 0; k < cnt; ++k) {           // wave-uniform loop
      int   wk = s_idx[wid][k];
      float vk = s_val[wid][k];
      if (lane < EDGE_F) mef += vk * erow[wk*EDGE_F + lane];
    }
  } else {                                    // general fallback: dense row
    for (int w = 0; w < NN; ++w) {
      float gv = grow[w];
      if (gv != 0.f && lane < EDGE_F) mef += gv * erow[w*EDGE_F + lane];
    }
  }
  if (lane < EDGE_F) me[(size_t)row*EDGE_F + lane] = mef;
  if (lane < KMAX && lane < cnt) {
    adj_idx[row*KMAX + lane] = s_idx[wid][lane];
    adj_val[row*KMAX + lane] = s_val[wid][lane];
  }
  if (lane == 0) {
    int bk = -1;                              // deg not in {1,2,3,4} -> h'=0
    if      (deg == 1.0f) bk = 0;
    else if (deg == 2.0f) bk = 1;
    else if (deg == 3.0f) bk = 2;
    else if (deg == 4.0f) bk = 3;
    bucketArr[row] = bk;
    nnzArr[row] = cnt;
  }
}

// ---------------------------------------------------------------------------
// K2: bucket-sort node ids so step blocks share one H matrix
// ---------------------------------------------------------------------------
__global__ void scatter_kernel(const int* __restrict__ bucketArr,
                               int* __restrict__ counts, int* __restrict__ perm)
{
  int i = blockIdx.x * blockDim.x + threadIdx.x;
  if (i < ROWS) {
    int bk = bucketArr[i];
    if (bk >= 0) {
      int p = atomicAdd(&counts[bk], 1);
      perm[bk*ROWS + p] = i;
    }
  }
}

// ---------------------------------------------------------------------------
// K3 (x3): register-tiled GEMM: 64 same-bucket nodes/block, 256 threads,
// thread computes 4 nodes x 4 outputs. msg staged TRANSPOSED [i][n] so node
// reads are ds_read_b128; H staged in LDS (20.5 KB, read as b128 broadcast).
// ---------------------------------------------------------------------------
__global__ __launch_bounds__(256) void step_kernel(
    const float* __restrict__ h_prev, float* __restrict__ h_out,
    const float* __restrict__ Ht,
    const int* __restrict__ perm, const int* __restrict__ counts,
    const int* __restrict__ nnzArr, const int* __restrict__ adj_idx,
    const float* __restrict__ adj_val, const float* __restrict__ me,
    const float* __restrict__ g)
{
  int d = blockIdx.x >> 8;                    // 256 chunks per bucket
  int chunk = blockIdx.x & 255;
  int cnt = counts[d];
  int base = chunk * 64;
  if (base >= cnt) return;                    // uniform early-exit
  __shared__ float smt[MSG][68];              // transposed msg [i][n], pad->bank-safe
  __shared__ float sH[MSG*OUTF];              // 80x64 = 20.5 KB
  __shared__ int   srow[64];
  int tid = threadIdx.x;
  int lane = tid & 63, wid = tid >> 6;
  { // stage H (L2-resident, 20.5 KB)
    const float4* H4 = (const float4*)(Ht + (size_t)d*MSG*OUTF);
    float4* s4 = (float4*)sH;
    for (int f = tid; f < MSG*OUTF/4; f += 256) s4[f] = H4[f];
  }
  // gather: wave wid handles nodes wid*16..+15, feature = lane
  for (int t = 0; t < 16; ++t) {
    int nl = wid*16 + t;
    int gi = base + nl;
    float mh = 0.f;
    int row = -1;
    if (gi < cnt) {
      row = perm[d*ROWS + gi];
      int bb = row >> 9;
      int nnz = nnzArr[row];
      if (nnz <= KMAX) {
        for (int k = 0; k < nnz; ++k) {
          int w = adj_idx[row*KMAX + k];
          float vv = adj_val[row*KMAX + k];
          mh += vv * h_prev[((size_t)(bb*NN + w))*NODE_F + lane];
        }
      } else {                                // general fallback
        const float* grow = g + (size_t)row * NN;
        for (int w = 0; w < NN; ++w) {
          float gv = grow[w];
          if (gv != 0.f) mh += gv * h_prev[((size_t)(bb*NN + w))*NODE_F + lane];
        }
      }
    }
    smt[lane][nl] = mh;
    if (lane < EDGE_F) smt[NODE_F + lane][nl] = (row >= 0) ? me[(size_t)row*EDGE_F + lane] : 0.f;
    if (lane == 0) srow[nl] = row;
  }
  __syncthreads();
  int tn = tid & 15, to = tid >> 4;           // nodes 4tn+k, outputs 4to+j
  float4 acc[4];
  acc[0] = acc[1] = acc[2] = acc[3] = make_float4(0.f,0.f,0.f,0.f);
  #pragma unroll 8
  for (int i = 0; i < MSG; ++i) {
    float4 hv = *(const float4*)&smt[i][4*tn];
    float4 wv = *(const float4*)&sH[i*OUTF + 4*to];
    float hk[4] = {hv.x, hv.y, hv.z, hv.w};
    #pragma unroll
    for (int k = 0; k < 4; ++k) {
      acc[k].x += hk[k]*wv.x; acc[k].y += hk[k]*wv.y;
      acc[k].z += hk[k]*wv.z; acc[k].w += hk[k]*wv.w;
    }
  }
  #pragma unroll
  for (int k = 0; k < 4; ++k) {
    int r = srow[4*tn + k];
    if (r >= 0) *(float4*)&h_out[(size_t)r*OUTF + 4*to] = acc[k];
  }
}

// ---------------------------------------------------------------------------
// K4: readout — register-tiled GEMM (64 nodes x 128 outs per block, thread =
// 4 nodes x 8 outs), then block-level masked softmax + accumulate into accv.
// h staged transposed [i][n]; reduction scratch OVERLAYS sht (post-sync).
// ---------------------------------------------------------------------------
__global__ __launch_bounds__(256) void readout_kernel(
    const float* __restrict__ h0, const float* __restrict__ h1,
    const float* __restrict__ h2, const float* __restrict__ h3,
    const float* __restrict__ W0, const float* __restrict__ W1,
    const float* __restrict__ W2, const float* __restrict__ W3,
    float* __restrict__ accv)
{
  int l = blockIdx.x >> 8;                    // 4 layers x 256 chunks
  int chunk = blockIdx.x & 255;
  const float* hs = (l==0)?h0:(l==1)?h1:(l==2)?h2:h3;
  const float* Wl = (l==0)?W0:(l==1)?W1:(l==2)?W2:W3;
  __shared__ float sW[NODE_F*RD];             // 32 KB
  __shared__ float sht[NODE_F*68];            // transposed h [i][n], 17.4 KB
  __shared__ float snmax[64], snsum[64];
  __shared__ int   snflag[64];
  float* redm = sht;                          // overlay (used post-GEMM, post-sync)
  int*   redf = (int*)(sht + 64*17);
  int tid = threadIdx.x;
  { // stage W (32 KB) and h-tile (16 KB, transposed)
    const float4* W4 = (const float4*)Wl;
    float4* sW4 = (float4*)sW;
    #pragma unroll
    for (int r = 0; r < 8; ++r) sW4[tid + 256*r] = W4[tid + 256*r];
    const float4* hv4 = (const float4*)(hs + (size_t)chunk*64*NODE_F);
    #pragma unroll
    for (int r = 0; r < 4; ++r) {
      int f = tid + 256*r;                    // f < 1024: n = f>>4, chunk4 = f&15
      int n = f >> 4, c = f & 15;
      float4 v = hv4[f];
      sht[(4*c+0)*68 + n] = v.x;
      sht[(4*c+1)*68 + n] = v.y;
      sht[(4*c+2)*68 + n] = v.z;
      sht[(4*c+3)*68 + n] = v.w;
    }
  }
  __syncthreads();
  int tn = tid & 15, to = tid >> 4;           // nodes 4tn+k, outputs 8to+j
  int b = chunk >> 3;                         // 8 chunks of 64 nodes per batch
  float4 accA[4], accB[4];
  #pragma unroll
  for (int k = 0; k < 4; ++k) { accA[k] = make_float4(0,0,0,0); accB[k] = make_float4(0,0,0,0); }
  #pragma unroll 4
  for (int i = 0; i < NODE_F; ++i) {
    float4 hv = *(const float4*)&sht[i*68 + 4*tn];
    float4 w0 = *(const float4*)&sW[i*128 + 8*to];
    float4 w1 = *(const float4*)&sW[i*128 + 8*to + 4];
    float hk[4] = {hv.x, hv.y, hv.z, hv.w};
    #pragma unroll
    for (int k = 0; k < 4; ++k) {
      accA[k].x += hk[k]*w0.x; accA[k].y += hk[k]*w0.y;
      accA[k].z += hk[k]*w0.z; accA[k].w += hk[k]*w0.w;
      accB[k].x += hk[k]*w1.x; accB[k].y += hk[k]*w1.y;
      accB[k].z += hk[k]*w1.z; accB[k].w += hk[k]*w1.w;
    }
  }
  __syncthreads();                            // sht reads done -> overlay writable
  // Pass A: per-thread partial max + nonzero flag per node
  #pragma unroll
  for (int k = 0; k < 4; ++k) {
    float4 a = accA[k], bq = accB[k];
    float pm = fmaxf(fmaxf(fmaxf(a.x,a.y),fmaxf(a.z,a.w)),
                     fmaxf(fmaxf(bq.x,bq.y),fmaxf(bq.z,bq.w)));
    int nz = (a.x!=0.f)||(a.y!=0.f)||(a.z!=0.f)||(a.w!=0.f)||
             (bq.x!=0.f)||(bq.y!=0.f)||(bq.z!=0.f)||(bq.w!=0.f);
    int n = 4*tn + k;
    redm[n*17 + to] = pm;
    redf[n*17 + to] = nz;
  }
  __syncthreads();
  // Pass B: 4 threads per node reduce 16 partials
  {
    int n = tid >> 2, sub = tid & 3;
    float m = redm[n*17 + sub*4 + 0];
    m = fmaxf(m, redm[n*17 + sub*4 + 1]);
    m = fmaxf(m, redm[n*17 + sub*4 + 2]);
    m = fmaxf(m, redm[n*17 + sub*4 + 3]);
    int f = redf[n*17 + sub*4 + 0] | redf[n*17 + sub*4 + 1] |
            redf[n*17 + sub*4 + 2] | redf[n*17 + sub*4 + 3];
    m = fmaxf(m, __shfl_xor(m, 1)); m = fmaxf(m, __shfl_xor(m, 2));
    f |= __shfl_xor(f, 1); f |= __shfl_xor(f, 2);
    if (sub == 0) { snmax[n] = m; snflag[n] = f; }
  }
  __syncthreads();
  // Pass C: exp in place + partial sums
  #pragma unroll
  for (int k = 0; k < 4; ++k) {
    int n = 4*tn + k;
    float m = snmax[n];
    accA[k].x = __expf(accA[k].x - m); accA[k].y = __expf(accA[k].y - m);
    accA[k].z = __expf(accA[k].z - m); accA[k].w = __expf(accA[k].w - m);
    accB[k].x = __expf(accB[k].x - m); accB[k].y = __expf(accB[k].y - m);
    accB[k].z = __expf(accB[k].z - m); accB[k].w = __expf(accB[k].w - m);
    float ps = accA[k].x+accA[k].y+accA[k].z+accA[k].w+
               accB[k].x+accB[k].y+accB[k].z+accB[k].w;
    redm[n*17 + to] = ps;
  }
  __syncthreads();
  // Pass D: node sums
  {
    int n = tid >> 2, sub = tid & 3;
    float s = redm[n*17 + sub*4 + 0] + redm[n*17 + sub*4 + 1] +
              redm[n*17 + sub*4 + 2] + redm[n*17 + sub*4 + 3];
    s += __shfl_xor(s, 1); s += __shfl_xor(s, 2);
    if (sub == 0) snsum[n] = s;
  }
  __syncthreads();
  // Pass E: accumulate p/s over this block's nodes, reduce over tn, atomicAdd
  float4 aj0 = make_float4(0,0,0,0), aj1 = make_float4(0,0,0,0);
  #pragma unroll
  for (int k = 0; k < 4; ++k) {
    int n = 4*tn + k;
    if (snflag[n]) {
      float inv = 1.0f / snsum[n];
      aj0.x += accA[k].x*inv; aj0.y += accA[k].y*inv;
      aj0.z += accA[k].z*inv; aj0.w += accA[k].w*inv;
      aj1.x += accB[k].x*inv; aj1.y += accB[k].y*inv;
      aj1.z += accB[k].z*inv; aj1.w += accB[k].w*inv;
    }
  }
  #pragma unroll
  for (int off = 1; off < 16; off <<= 1) {
    aj0.x += __shfl_xor(aj0.x, off); aj0.y += __shfl_xor(aj0.y, off);
    aj0.z += __shfl_xor(aj0.z, off); aj0.w += __shfl_xor(aj0.w, off);
    aj1.x += __shfl_xor(aj1.x, off); aj1.y += __shfl_xor(aj1.y, off);
    aj1.z += __shfl_xor(aj1.z, off); aj1.w += __shfl_xor(aj1.w, off);
  }
  if (tn == 0) {
    float* dst = &accv[b*RD + 8*to];
    atomicAdd(dst+0, aj0.x); atomicAdd(dst+1, aj0.y);
    atomicAdd(dst+2, aj0.z); atomicAdd(dst+3, aj0.w);
    atomicAdd(dst+4, aj1.x); atomicAdd(dst+5, aj1.y);
    atomicAdd(dst+6, aj1.z); atomicAdd(dst+7, aj1.w);
  }
}

// ---------------------------------------------------------------------------
// K5: out[b] = softmax(acc[b] @ W_final + b_final); one block per batch
// ---------------------------------------------------------------------------
__global__ __launch_bounds__(256) void final_kernel(
    const float* __restrict__ accv, const float* __restrict__ Wf,
    const float* __restrict__ bf, float* __restrict__ out)
{
  int b = blockIdx.x;
  int tid = threadIdx.x;
  int tg = tid & 15, part = tid >> 4;         // 16 parts x 8 i's each
  float p = 0.f;
  #pragma unroll
  for (int q = 0; q < 8; ++q) {
    int i = part*8 + q;
    p += accv[b*RD + i] * Wf[i*TGT + tg];
  }
  __shared__ float pp[16][17];
  pp[part][tg] = p;
  __syncthreads();
  if (tid < 16) {
    float v = bf[tid];
    #pragma unroll
    for (int q = 0; q < 16; ++q) v += pp[q][tid];
    float mx = v;
    for (int off = 8; off; off >>= 1) mx = fmaxf(mx, __shfl_xor(mx, off, 16));
    float e = __expf(v - mx);
    float s = e;
    for (int off = 8; off; off >>= 1) s += __shfl_xor(s, off, 16);
    out[b*TGT + tid] = e / s;
  }
}

extern "C" void kernel_launch(void* const* d_in, const int* in_sizes, int n_in,
                              void* d_out, int out_size, void* d_ws, size_t ws_size,
                              hipStream_t stream)
{
  const float* g    = (const float*)d_in[0];
  const float* h_in = (const float*)d_in[1];
  const float* e    = (const float*)d_in[2];
  const float* H0   = (const float*)d_in[3];
  const float* H1   = (const float*)d_in[4];
  const float* H2   = (const float*)d_in[5];
  const float* W0   = (const float*)d_in[6];
  const float* W1   = (const float*)d_in[7];
  const float* W2   = (const float*)d_in[8];
  const float* W3   = (const float*)d_in[9];
  const float* Wf   = (const float*)d_in[10];
  const float* bf   = (const float*)d_in[11];
  float* out = (float*)d_out;

  char* base = (char*)d_ws;
  size_t off = 0;
  auto alloc = [&](size_t bytes) -> void* {
    void* p = base + off;
    off = (off + bytes + 255) & ~(size_t)255;
    return p;
  };
  int*   adj_idx   = (int*)  alloc((size_t)ROWS*KMAX*sizeof(int));
  float* adj_val   = (float*)alloc((size_t)ROWS*KMAX*sizeof(float));
  int*   nnzArr    = (int*)  alloc((size_t)ROWS*sizeof(int));
  int*   bucketArr = (int*)  alloc((size_t)ROWS*sizeof(int));
  float* me        = (float*)alloc((size_t)ROWS*EDGE_F*sizeof(float));
  int*   perm      = (int*)  alloc((size_t)4*ROWS*sizeof(int));
  int*   counts    = (int*)  alloc(4*sizeof(int) + (size_t)BATCH*RD*sizeof(float));
  float* accv      = (float*)(counts + 4);
  float* h1        = (float*)alloc((size_t)ROWS*NODE_F*sizeof(float)*3);
  float* h2 = h1 + (size_t)ROWS*NODE_F;
  float* h3 = h2 + (size_t)ROWS*NODE_F;

  // zero counts+acc and h1..h3 (bucket<0 nodes must read as 0)
  hipMemsetAsync(counts, 0, 4*sizeof(int) + (size_t)BATCH*RD*sizeof(float), stream);
  hipMemsetAsync(h1, 0, (size_t)ROWS*NODE_F*sizeof(float)*3, stream);

  preprocess_kernel<<<ROWS/4, 256, 0, stream>>>(g, e, adj_idx, adj_val, nnzArr, bucketArr, me);
  scatter_kernel<<<ROWS/256, 256, 0, stream>>>(bucketArr, counts, perm);
  step_kernel<<<4*256, 256, 0, stream>>>(h_in, h1, H0, perm, counts, nnzArr, adj_idx, adj_val, me, g);
  step_kernel<<<4*256, 256, 0, stream>>>(h1,   h2, H1, perm, counts, nnzArr, adj_idx, adj_val, me, g);
  step_kernel<<<4*256, 256, 0, stream>>>(h2,   h3, H2, perm, counts, nnzArr, adj_idx, adj_val, me, g);
  readout_kernel<<<4*256, 256, 0, stream>>>(h_in, h1, h2, h3, W0, W1, W2, W3, accv);
  final_kernel<<<BATCH, 256, 0, stream>>>(accv, Wf, bf, out);
}

// Round 3
// 788.224 us; speedup vs baseline: 1.1459x; 1.1041x over previous
//
#include <hip/hip_runtime.h>

#define BATCH 32
#define NN 512
#define NODE_F 64
#define EDGE_F 16
#define MSG 80        // NODE_F + EDGE_F
#define OUTF 64
#define RD 128        // readout dim (OUT[3])
#define TGT 16
#define KMAX 8        // compact-adjacency cap; fallback to dense scan beyond
#define ROWS (BATCH*NN)  // 16384

// ---------------------------------------------------------------------------
// K1: per (b,v) row of g: degree, compact adjacency (<=KMAX), me = sum g*e
// one wave (64 lanes) per row; 4 waves per 256-thread block
// ---------------------------------------------------------------------------
__global__ __launch_bounds__(256) void preprocess_kernel(
    const float* __restrict__ g, const float* __restrict__ e,
    int* __restrict__ adj_idx, float* __restrict__ adj_val,
    int* __restrict__ nnzArr, int* __restrict__ bucketArr,
    float* __restrict__ me)
{
  __shared__ int   s_idx[4][KMAX];
  __shared__ float s_val[4][KMAX];
  int lane = threadIdx.x & 63;
  int wid  = threadIdx.x >> 6;
  int row  = blockIdx.x * 4 + wid;
  const float* grow = g + (size_t)row * NN;
  float deg = 0.f;
  int cnt = 0;
  for (int it = 0; it < NN/64; ++it) {        // uniform trip count
    int w = it*64 + lane;
    float gv = grow[w];
    deg += gv;
    unsigned long long m = __ballot(gv != 0.0f);
    int before = __popcll(m & ((1ull << lane) - 1ull));
    if (gv != 0.0f) {
      int pos = cnt + before;
      if (pos < KMAX) { s_idx[wid][pos] = w; s_val[wid][pos] = gv; }
    }
    cnt += __popcll(m);
  }
  for (int off = 32; off; off >>= 1) deg += __shfl_xor(deg, off);
  __syncthreads();
  const float* erow = e + (size_t)row * NN * EDGE_F;
  float mef = 0.f;
  if (cnt <= KMAX) {
    for (int k = 0; k < cnt; ++k) {           // wave-uniform loop
      int   wk = s_idx[wid][k];
      float vk = s_val[wid][k];
      if (lane < EDGE_F) mef += vk * erow[wk*EDGE_F + lane];
    }
  } else {                                    // general fallback: dense row
    for (int w = 0; w < NN; ++w) {
      float gv = grow[w];
      if (gv != 0.f && lane < EDGE_F) mef += gv * erow[w*EDGE_F + lane];
    }
  }
  if (lane < EDGE_F) me[(size_t)row*EDGE_F + lane] = mef;
  if (lane < KMAX && lane < cnt) {
    adj_idx[row*KMAX + lane] = s_idx[wid][lane];
    adj_val[row*KMAX + lane] = s_val[wid][lane];
  }
  if (lane == 0) {
    int bk = -1;                              // deg not in {1,2,3,4} -> h'=0
    if      (deg == 1.0f) bk = 0;
    else if (deg == 2.0f) bk = 1;
    else if (deg == 3.0f) bk = 2;
    else if (deg == 4.0f) bk = 3;
    bucketArr[row] = bk;
    nnzArr[row] = cnt;
  }
}

// ---------------------------------------------------------------------------
// K2: bucket-sort node ids. WAVE-AGGREGATED: one atomicAdd per (wave,bucket)
// instead of one per thread (16384 -> <=1024 atomics on 4 hot addresses).
// ---------------------------------------------------------------------------
__global__ __launch_bounds__(256) void scatter_kernel(
    const int* __restrict__ bucketArr,
    int* __restrict__ counts, int* __restrict__ perm)
{
  int i = blockIdx.x * blockDim.x + threadIdx.x;
  int lane = threadIdx.x & 63;
  int bk = bucketArr[i];                      // grid == ROWS exactly
  #pragma unroll
  for (int d = 0; d < 4; ++d) {
    unsigned long long m = __ballot(bk == d);
    if (m == 0ull) continue;                  // wave-uniform
    int leader = __ffsll((long long)m) - 1;
    int tot    = __popcll(m);
    int base = 0;
    if (lane == leader) base = atomicAdd(&counts[d], tot);
    base = __shfl(base, leader);
    if (bk == d) {
      int before = __popcll(m & ((1ull << lane) - 1ull));
      perm[d*ROWS + base + before] = i;       // coalesced segment per wave
    }
  }
}

// ---------------------------------------------------------------------------
// K3 (x3): register-tiled GEMM: 64 same-bucket nodes/block, 256 threads,
// thread computes 4 nodes x 4 outputs. msg staged TRANSPOSED [i][n] so node
// reads are ds_read_b128; H staged in LDS (20.5 KB, read as b128 broadcast).
// ---------------------------------------------------------------------------
__global__ __launch_bounds__(256) void step_kernel(
    const float* __restrict__ h_prev, float* __restrict__ h_out,
    const float* __restrict__ Ht,
    const int* __restrict__ perm, const int* __restrict__ counts,
    const int* __restrict__ nnzArr, const int* __restrict__ adj_idx,
    const float* __restrict__ adj_val, const float* __restrict__ me,
    const float* __restrict__ g)
{
  int d = blockIdx.x >> 8;                    // 256 chunks per bucket
  int chunk = blockIdx.x & 255;
  int cnt = counts[d];
  int base = chunk * 64;
  if (base >= cnt) return;                    // uniform early-exit
  __shared__ float smt[MSG][68];              // transposed msg [i][n]
  __shared__ float sH[MSG*OUTF];              // 80x64 = 20.5 KB
  __shared__ int   srow[64];
  int tid = threadIdx.x;
  int lane = tid & 63, wid = tid >> 6;
  { // stage H (L2-resident, 20.5 KB)
    const float4* H4 = (const float4*)(Ht + (size_t)d*MSG*OUTF);
    float4* s4 = (float4*)sH;
    for (int f = tid; f < MSG*OUTF/4; f += 256) s4[f] = H4[f];
  }
  // gather: wave wid handles nodes wid*16..+15, feature = lane
  for (int t = 0; t < 16; ++t) {
    int nl = wid*16 + t;
    int gi = base + nl;
    float mh = 0.f;
    int row = -1;
    if (gi < cnt) {
      row = perm[d*ROWS + gi];
      int bb = row >> 9;
      int nnz = nnzArr[row];
      if (nnz <= KMAX) {
        for (int k = 0; k < nnz; ++k) {
          int w = adj_idx[row*KMAX + k];
          float vv = adj_val[row*KMAX + k];
          mh += vv * h_prev[((size_t)(bb*NN + w))*NODE_F + lane];
        }
      } else {                                // general fallback
        const float* grow = g + (size_t)row * NN;
        for (int w = 0; w < NN; ++w) {
          float gv = grow[w];
          if (gv != 0.f) mh += gv * h_prev[((size_t)(bb*NN + w))*NODE_F + lane];
        }
      }
    }
    smt[lane][nl] = mh;
    if (lane < EDGE_F) smt[NODE_F + lane][nl] = (row >= 0) ? me[(size_t)row*EDGE_F + lane] : 0.f;
    if (lane == 0) srow[nl] = row;
  }
  __syncthreads();
  int tn = tid & 15, to = tid >> 4;           // nodes 4tn+k, outputs 4to+j
  float4 acc[4];
  acc[0] = acc[1] = acc[2] = acc[3] = make_float4(0.f,0.f,0.f,0.f);
  #pragma unroll 8
  for (int i = 0; i < MSG; ++i) {
    float4 hv = *(const float4*)&smt[i][4*tn];
    float4 wv = *(const float4*)&sH[i*OUTF + 4*to];
    float hk[4] = {hv.x, hv.y, hv.z, hv.w};
    #pragma unroll
    for (int k = 0; k < 4; ++k) {
      acc[k].x += hk[k]*wv.x; acc[k].y += hk[k]*wv.y;
      acc[k].z += hk[k]*wv.z; acc[k].w += hk[k]*wv.w;
    }
  }
  #pragma unroll
  for (int k = 0; k < 4; ++k) {
    int r = srow[4*tn + k];
    if (r >= 0) *(float4*)&h_out[(size_t)r*OUTF + 4*to] = acc[k];
  }
}

// ---------------------------------------------------------------------------
// K4: readout — register-tiled GEMM (64 nodes x 128 outs per block, thread =
// 4 nodes x 8 outs), then block-level masked softmax + accumulate into accv.
// h staged transposed [i][n]; reduction scratch OVERLAYS sht (post-sync).
// ---------------------------------------------------------------------------
__global__ __launch_bounds__(256) void readout_kernel(
    const float* __restrict__ h0, const float* __restrict__ h1,
    const float* __restrict__ h2, const float* __restrict__ h3,
    const float* __restrict__ W0, const float* __restrict__ W1,
    const float* __restrict__ W2, const float* __restrict__ W3,
    float* __restrict__ accv)
{
  int l = blockIdx.x >> 8;                    // 4 layers x 256 chunks
  int chunk = blockIdx.x & 255;
  const float* hs = (l==0)?h0:(l==1)?h1:(l==2)?h2:h3;
  const float* Wl = (l==0)?W0:(l==1)?W1:(l==2)?W2:W3;
  __shared__ float sW[NODE_F*RD];             // 32 KB
  __shared__ float sht[NODE_F*68];            // transposed h [i][n], 17.4 KB
  __shared__ float snmax[64], snsum[64];
  __shared__ int   snflag[64];
  float* redm = sht;                          // overlay (used post-GEMM, post-sync)
  int*   redf = (int*)(sht + 64*17);
  int tid = threadIdx.x;
  { // stage W (32 KB) and h-tile (16 KB, transposed)
    const float4* W4 = (const float4*)Wl;
    float4* sW4 = (float4*)sW;
    #pragma unroll
    for (int r = 0; r < 8; ++r) sW4[tid + 256*r] = W4[tid + 256*r];
    const float4* hv4 = (const float4*)(hs + (size_t)chunk*64*NODE_F);
    #pragma unroll
    for (int r = 0; r < 4; ++r) {
      int f = tid + 256*r;                    // f < 1024: n = f>>4, chunk4 = f&15
      int n = f >> 4, c = f & 15;
      float4 v = hv4[f];
      sht[(4*c+0)*68 + n] = v.x;
      sht[(4*c+1)*68 + n] = v.y;
      sht[(4*c+2)*68 + n] = v.z;
      sht[(4*c+3)*68 + n] = v.w;
    }
  }
  __syncthreads();
  int tn = tid & 15, to = tid >> 4;           // nodes 4tn+k, outputs 8to+j
  int b = chunk >> 3;                         // 8 chunks of 64 nodes per batch
  float4 accA[4], accB[4];
  #pragma unroll
  for (int k = 0; k < 4; ++k) { accA[k] = make_float4(0,0,0,0); accB[k] = make_float4(0,0,0,0); }
  #pragma unroll 4
  for (int i = 0; i < NODE_F; ++i) {
    float4 hv = *(const float4*)&sht[i*68 + 4*tn];
    float4 w0 = *(const float4*)&sW[i*128 + 8*to];
    float4 w1 = *(const float4*)&sW[i*128 + 8*to + 4];
    float hk[4] = {hv.x, hv.y, hv.z, hv.w};
    #pragma unroll
    for (int k = 0; k < 4; ++k) {
      accA[k].x += hk[k]*w0.x; accA[k].y += hk[k]*w0.y;
      accA[k].z += hk[k]*w0.z; accA[k].w += hk[k]*w0.w;
      accB[k].x += hk[k]*w1.x; accB[k].y += hk[k]*w1.y;
      accB[k].z += hk[k]*w1.z; accB[k].w += hk[k]*w1.w;
    }
  }
  __syncthreads();                            // sht reads done -> overlay writable
  // Pass A: per-thread partial max + nonzero flag per node
  #pragma unroll
  for (int k = 0; k < 4; ++k) {
    float4 a = accA[k], bq = accB[k];
    float pm = fmaxf(fmaxf(fmaxf(a.x,a.y),fmaxf(a.z,a.w)),
                     fmaxf(fmaxf(bq.x,bq.y),fmaxf(bq.z,bq.w)));
    int nz = (a.x!=0.f)||(a.y!=0.f)||(a.z!=0.f)||(a.w!=0.f)||
             (bq.x!=0.f)||(bq.y!=0.f)||(bq.z!=0.f)||(bq.w!=0.f);
    int n = 4*tn + k;
    redm[n*17 + to] = pm;
    redf[n*17 + to] = nz;
  }
  __syncthreads();
  // Pass B: 4 threads per node reduce 16 partials
  {
    int n = tid >> 2, sub = tid & 3;
    float m = redm[n*17 + sub*4 + 0];
    m = fmaxf(m, redm[n*17 + sub*4 + 1]);
    m = fmaxf(m, redm[n*17 + sub*4 + 2]);
    m = fmaxf(m, redm[n*17 + sub*4 + 3]);
    int f = redf[n*17 + sub*4 + 0] | redf[n*17 + sub*4 + 1] |
            redf[n*17 + sub*4 + 2] | redf[n*17 + sub*4 + 3];
    m = fmaxf(m, __shfl_xor(m, 1)); m = fmaxf(m, __shfl_xor(m, 2));
    f |= __shfl_xor(f, 1); f |= __shfl_xor(f, 2);
    if (sub == 0) { snmax[n] = m; snflag[n] = f; }
  }
  __syncthreads();
  // Pass C: exp in place + partial sums
  #pragma unroll
  for (int k = 0; k < 4; ++k) {
    int n = 4*tn + k;
    float m = snmax[n];
    accA[k].x = __expf(accA[k].x - m); accA[k].y = __expf(accA[k].y - m);
    accA[k].z = __expf(accA[k].z - m); accA[k].w = __expf(accA[k].w - m);
    accB[k].x = __expf(accB[k].x - m); accB[k].y = __expf(accB[k].y - m);
    accB[k].z = __expf(accB[k].z - m); accB[k].w = __expf(accB[k].w - m);
    float ps = accA[k].x+accA[k].y+accA[k].z+accA[k].w+
               accB[k].x+accB[k].y+accB[k].z+accB[k].w;
    redm[n*17 + to] = ps;
  }
  __syncthreads();
  // Pass D: node sums
  {
    int n = tid >> 2, sub = tid & 3;
    float s = redm[n*17 + sub*4 + 0] + redm[n*17 + sub*4 + 1] +
              redm[n*17 + sub*4 + 2] + redm[n*17 + sub*4 + 3];
    s += __shfl_xor(s, 1); s += __shfl_xor(s, 2);
    if (sub == 0) snsum[n] = s;
  }
  __syncthreads();
  // Pass E: accumulate p/s over this block's nodes, reduce over tn, atomicAdd
  float4 aj0 = make_float4(0,0,0,0), aj1 = make_float4(0,0,0,0);
  #pragma unroll
  for (int k = 0; k < 4; ++k) {
    int n = 4*tn + k;
    if (snflag[n]) {
      float inv = 1.0f / snsum[n];
      aj0.x += accA[k].x*inv; aj0.y += accA[k].y*inv;
      aj0.z += accA[k].z*inv; aj0.w += accA[k].w*inv;
      aj1.x += accB[k].x*inv; aj1.y += accB[k].y*inv;
      aj1.z += accB[k].z*inv; aj1.w += accB[k].w*inv;
    }
  }
  #pragma unroll
  for (int off = 1; off < 16; off <<= 1) {
    aj0.x += __shfl_xor(aj0.x, off); aj0.y += __shfl_xor(aj0.y, off);
    aj0.z += __shfl_xor(aj0.z, off); aj0.w += __shfl_xor(aj0.w, off);
    aj1.x += __shfl_xor(aj1.x, off); aj1.y += __shfl_xor(aj1.y, off);
    aj1.z += __shfl_xor(aj1.z, off); aj1.w += __shfl_xor(aj1.w, off);
  }
  if (tn == 0) {
    float* dst = &accv[b*RD + 8*to];
    atomicAdd(dst+0, aj0.x); atomicAdd(dst+1, aj0.y);
    atomicAdd(dst+2, aj0.z); atomicAdd(dst+3, aj0.w);
    atomicAdd(dst+4, aj1.x); atomicAdd(dst+5, aj1.y);
    atomicAdd(dst+6, aj1.z); atomicAdd(dst+7, aj1.w);
  }
}

// ---------------------------------------------------------------------------
// K5: out[b] = softmax(acc[b] @ W_final + b_final); one block per batch
// ---------------------------------------------------------------------------
__global__ __launch_bounds__(256) void final_kernel(
    const float* __restrict__ accv, const float* __restrict__ Wf,
    const float* __restrict__ bf, float* __restrict__ out)
{
  int b = blockIdx.x;
  int tid = threadIdx.x;
  int tg = tid & 15, part = tid >> 4;         // 16 parts x 8 i's each
  float p = 0.f;
  #pragma unroll
  for (int q = 0; q < 8; ++q) {
    int i = part*8 + q;
    p += accv[b*RD + i] * Wf[i*TGT + tg];
  }
  __shared__ float pp[16][17];
  pp[part][tg] = p;
  __syncthreads();
  if (tid < 16) {
    float v = bf[tid];
    #pragma unroll
    for (int q = 0; q < 16; ++q) v += pp[q][tid];
    float mx = v;
    for (int off = 8; off; off >>= 1) mx = fmaxf(mx, __shfl_xor(mx, off, 16));
    float e = __expf(v - mx);
    float s = e;
    for (int off = 8; off; off >>= 1) s += __shfl_xor(s, off, 16);
    out[b*TGT + tid] = e / s;
  }
}

extern "C" void kernel_launch(void* const* d_in, const int* in_sizes, int n_in,
                              void* d_out, int out_size, void* d_ws, size_t ws_size,
                              hipStream_t stream)
{
  const float* g    = (const float*)d_in[0];
  const float* h_in = (const float*)d_in[1];
  const float* e    = (const float*)d_in[2];
  const float* H0   = (const float*)d_in[3];
  const float* H1   = (const float*)d_in[4];
  const float* H2   = (const float*)d_in[5];
  const float* W0   = (const float*)d_in[6];
  const float* W1   = (const float*)d_in[7];
  const float* W2   = (const float*)d_in[8];
  const float* W3   = (const float*)d_in[9];
  const float* Wf   = (const float*)d_in[10];
  const float* bf   = (const float*)d_in[11];
  float* out = (float*)d_out;

  char* base = (char*)d_ws;
  size_t off = 0;
  auto alloc = [&](size_t bytes) -> void* {
    void* p = base + off;
    off = (off + bytes + 255) & ~(size_t)255;
    return p;
  };
  int*   adj_idx   = (int*)  alloc((size_t)ROWS*KMAX*sizeof(int));
  float* adj_val   = (float*)alloc((size_t)ROWS*KMAX*sizeof(float));
  int*   nnzArr    = (int*)  alloc((size_t)ROWS*sizeof(int));
  int*   bucketArr = (int*)  alloc((size_t)ROWS*sizeof(int));
  float* me        = (float*)alloc((size_t)ROWS*EDGE_F*sizeof(float));
  int*   perm      = (int*)  alloc((size_t)4*ROWS*sizeof(int));
  int*   counts    = (int*)  alloc(4*sizeof(int) + (size_t)BATCH*RD*sizeof(float));
  float* accv      = (float*)(counts + 4);
  float* h1        = (float*)alloc((size_t)ROWS*NODE_F*sizeof(float)*3);
  float* h2 = h1 + (size_t)ROWS*NODE_F;
  float* h3 = h2 + (size_t)ROWS*NODE_F;

  // zero counts+acc and h1..h3 (bucket<0 nodes must read as 0)
  hipMemsetAsync(counts, 0, 4*sizeof(int) + (size_t)BATCH*RD*sizeof(float), stream);
  hipMemsetAsync(h1, 0, (size_t)ROWS*NODE_F*sizeof(float)*3, stream);

  preprocess_kernel<<<ROWS/4, 256, 0, stream>>>(g, e, adj_idx, adj_val, nnzArr, bucketArr, me);
  scatter_kernel<<<ROWS/256, 256, 0, stream>>>(bucketArr, counts, perm);
  step_kernel<<<4*256, 256, 0, stream>>>(h_in, h1, H0, perm, counts, nnzArr, adj_idx, adj_val, me, g);
  step_kernel<<<4*256, 256, 0, stream>>>(h1,   h2, H1, perm, counts, nnzArr, adj_idx, adj_val, me, g);
  step_kernel<<<4*256, 256, 0, stream>>>(h2,   h3, H2, perm, counts, nnzArr, adj_idx, adj_val, me, g);
  readout_kernel<<<4*256, 256, 0, stream>>>(h_in, h1, h2, h3, W0, W1, W2, W3, accv);
  final_kernel<<<BATCH, 256, 0, stream>>>(accv, Wf, bf, out);
}